// Round 9
// baseline (596.614 us; speedup 1.0000x reference)
//
#include <hip/hip_runtime.h>
#include <hip/hip_bf16.h>

typedef __bf16 v8bf __attribute__((ext_vector_type(8)));
typedef float  v4f  __attribute__((ext_vector_type(4)));

constexpr int N_NODES = 50000;
constexpr int N_EDGES = 800000;
constexpr float LN_EPS = 1e-6f;
constexpr int ROW_TILES = N_NODES / 16;   // 3125, exact

// ---------------- int-width probe (robust to int32/int64 device ints) ----------------
__global__ void probe_kernel(const int* __restrict__ edge, int* __restrict__ flag) {
  int t = threadIdx.x;           // 64 lanes
  int nz = 0;
  for (int i = t * 2 + 1; i < 4096; i += 128) nz |= (edge[i] != 0);
  unsigned long long m = __ballot(nz);
  if (t == 0) flag[0] = (m == 0ull) ? 1 : 0;
}

__device__ __forceinline__ int ld_idx(const void* base, int i, int is64) {
  int v;
  if (is64) v = (int)((const long long*)base)[(long long)i];
  else      v = ((const int*)base)[i];
  if ((unsigned)v >= (unsigned)N_NODES) v = 0;   // defensive clamp
  return v;
}

// ---------------- graph preprocessing ----------------

__global__ void init_kernel(int* __restrict__ deg, int* __restrict__ gcount) {
  int i = blockIdx.x * 256 + threadIdx.x;
  if (i < N_NODES) deg[i] = 1;              // self-loop
  if (i == 0) gcount[0] = 0;
}

__global__ void count_kernel(const void* __restrict__ edge, const int* __restrict__ flag,
                             int* __restrict__ deg) {
  int e = blockIdx.x * 256 + threadIdx.x;
  if (e < N_EDGES) atomicAdd(&deg[ld_idx(edge, N_EDGES + e, flag[0])], 1);
}

__global__ __launch_bounds__(256) void block_offsets_kernel(
    const int* __restrict__ deg, int* __restrict__ gcount,
    int* __restrict__ rowstart, int* __restrict__ cursor, float* __restrict__ dinv) {
  __shared__ int ps[256];
  __shared__ int base_s;
  int tid = threadIdx.x;
  int node = blockIdx.x * 256 + tid;
  int d = (node < N_NODES) ? deg[node] : 1;
  int cnt = d - 1;                           // real in-edges for this node
  ps[tid] = cnt;
  __syncthreads();
#pragma unroll
  for (int off = 1; off < 256; off <<= 1) {
    int v = (tid >= off) ? ps[tid - off] : 0;
    __syncthreads();
    ps[tid] += v;
    __syncthreads();
  }
  if (tid == 255) base_s = atomicAdd(gcount, ps[255]);
  __syncthreads();
  int start = base_s + ps[tid] - cnt;        // exclusive within block + block base
  if (node < N_NODES) {
    rowstart[node] = start;
    cursor[node]   = start;
    dinv[node]     = rsqrtf((float)max(d, 1));
  }
}

__global__ void scatter_kernel(const void* __restrict__ edge, const int* __restrict__ flag,
                               int* __restrict__ cursor, int* __restrict__ csr_src) {
  int e = blockIdx.x * 256 + threadIdx.x;
  if (e >= N_EDGES) return;
  int f = flag[0];
  int s = ld_idx(edge, e, f);
  int d = ld_idx(edge, N_EDGES + e, f);
  int pos = atomicAdd(&cursor[d], 1);
  if ((unsigned)pos < (unsigned)N_EDGES) csr_src[pos] = s;
}

// ---------------- weight packing (fp32 -> bf16 MFMA B-fragment layout) ----------------
// Wp sections: W0c0[0] W0c1[32768] W1c0[65536] W1c1[131072] W2c0[196608] W2c1[262144]
// Within a section: Wp[((kc*16 + ct)*64 + lane)*8 + j] = W[kc*32 + (lane>>4)*8 + j][ct*16 + (lane&15)]
__global__ void pack_all_kernel(const float* __restrict__ W0, const float* __restrict__ W1,
                                const float* __restrict__ W2, __bf16* __restrict__ Wp) {
  int tid = blockIdx.x * 256 + threadIdx.x;   // 327680 threads exactly (1280 blocks)
  const float* src; int local;
  if (tid < 65536)       { src = W0 + (size_t)(tid >> 15) * (128 * 256); local = tid & 32767; }
  else if (tid < 196608) { int t2 = tid - 65536;  src = W1 + (size_t)(t2 >> 16) * 65536; local = t2 & 65535; }
  else                   { int t2 = tid - 196608; src = W2 + (size_t)(t2 >> 16) * 65536; local = t2 & 65535; }
  int j    = local & 7;
  int lane = (local >> 3) & 63;
  int ct   = (local >> 9) & 15;
  int kc   = local >> 13;
  int k    = kc * 32 + ((lane >> 4) << 3) + j;
  int col  = ct * 16 + (lane & 15);
  Wp[tid] = (__bf16)src[k * 256 + col];
}

// ---------------- x pre-scale: xd[i] = bf16(dinv[i] * x[i]), 128 dims ----------------
__global__ __launch_bounds__(256) void prescale_x_kernel(
    const float* __restrict__ x, const float* __restrict__ dinv, __bf16* __restrict__ xd) {
  int t = blockIdx.x * 256 + threadIdx.x;   // 800000 threads exactly
  int node = t >> 4;
  int d0 = (t & 15) * 8;
  float di = dinv[node];
  v4f f0 = *(const v4f*)(x + (size_t)node * 128 + d0);
  v4f f1 = *(const v4f*)(x + (size_t)node * 128 + d0 + 4);
  v8bf o;
#pragma unroll
  for (int j = 0; j < 4; j++) { o[j] = (__bf16)(di * f0[j]); o[4 + j] = (__bf16)(di * f1[j]); }
  *(v8bf*)(xd + (size_t)node * 128 + d0) = o;
}

// ---------------- FUSED layer-0: gather(xd,128) -> LDS tile -> dual GEMM K=128 ------
// Block owns 16 nodes. Phase 1: DYNAMIC node pool (LDS atomic) — waves grab nodes,
// killing the max-of-fixed-assignment straggler (Poisson-degree variance).
// Gather uses the verified agg128 pattern (16 lanes/row, 4 edge slots).
// Phase 2: wave (ch,q) computes 128 output cols of channel ch from LDS + packed W.
__global__ __launch_bounds__(256) void fused0_kernel(
    const __bf16* __restrict__ Yd, const int* __restrict__ rowstart,
    const int* __restrict__ deg, const int* __restrict__ csr_src,
    const float* __restrict__ dinv, const __bf16* __restrict__ Wp,   // W0 base (2 sections)
    const float* __restrict__ bias,                                  // [2,256]
    __bf16* __restrict__ Hd) {                                       // [N,512] interleaved
  __shared__ __bf16 lds[16 * 128];   // 4 KB
  __shared__ int wcnt;
  char* lb = (char*)lds;
  int wave = threadIdx.x >> 6;
  int lane = threadIdx.x & 63;
  int sub = lane >> 4;
  int dc = (lane & 15) * 8;
  if (threadIdx.x == 0) wcnt = 0;
  __syncthreads();

  // ---- phase 1: dynamic node pool ----
  for (;;) {
    int row;
    if (lane == 0) row = atomicAdd(&wcnt, 1);
    row = __shfl(row, 0);
    if (row >= 16) break;
    int node = blockIdx.x * 16 + row;

    int start = rowstart[node];
    int cnt = deg[node] - 1;
    start = max(0, min(start, N_EDGES));
    cnt = max(0, min(cnt, N_EDGES - start));
    int e = start, end = start + cnt;

    float di = dinv[node];
    v8bf ys = *(const v8bf*)(Yd + (unsigned)(node * 128 + dc));

    float a[8];
#pragma unroll
    for (int j = 0; j < 8; j++) a[j] = 0.f;

    for (; e + 16 <= end; e += 16) {
      int s0 = csr_src[e + sub];
      int s1 = csr_src[e + 4 + sub];
      int s2 = csr_src[e + 8 + sub];
      int s3 = csr_src[e + 12 + sub];
      if ((unsigned)s0 >= (unsigned)N_NODES) s0 = 0;
      if ((unsigned)s1 >= (unsigned)N_NODES) s1 = 0;
      if ((unsigned)s2 >= (unsigned)N_NODES) s2 = 0;
      if ((unsigned)s3 >= (unsigned)N_NODES) s3 = 0;
      v8bf y0 = *(const v8bf*)(Yd + (unsigned)(s0 * 128 + dc));
      v8bf y1 = *(const v8bf*)(Yd + (unsigned)(s1 * 128 + dc));
      v8bf y2 = *(const v8bf*)(Yd + (unsigned)(s2 * 128 + dc));
      v8bf y3 = *(const v8bf*)(Yd + (unsigned)(s3 * 128 + dc));
#pragma unroll
      for (int j = 0; j < 8; j++)
        a[j] += ((float)y0[j] + (float)y1[j]) + ((float)y2[j] + (float)y3[j]);
    }
    if (e + 8 <= end) {
      int s0 = csr_src[e + sub];
      int s1 = csr_src[e + 4 + sub];
      if ((unsigned)s0 >= (unsigned)N_NODES) s0 = 0;
      if ((unsigned)s1 >= (unsigned)N_NODES) s1 = 0;
      v8bf y0 = *(const v8bf*)(Yd + (unsigned)(s0 * 128 + dc));
      v8bf y1 = *(const v8bf*)(Yd + (unsigned)(s1 * 128 + dc));
#pragma unroll
      for (int j = 0; j < 8; j++) a[j] += (float)y0[j] + (float)y1[j];
      e += 8;
    }
    if (e + 4 <= end) {
      int s0 = csr_src[e + sub];
      if ((unsigned)s0 >= (unsigned)N_NODES) s0 = 0;
      v8bf y0 = *(const v8bf*)(Yd + (unsigned)(s0 * 128 + dc));
#pragma unroll
      for (int j = 0; j < 8; j++) a[j] += (float)y0[j];
      e += 4;
    }
    int rem = end - e;
    if (sub < rem) {
      int s0 = csr_src[e + sub];
      if ((unsigned)s0 >= (unsigned)N_NODES) s0 = 0;
      v8bf y0 = *(const v8bf*)(Yd + (unsigned)(s0 * 128 + dc));
#pragma unroll
      for (int j = 0; j < 8; j++) a[j] += (float)y0[j];
    }

#pragma unroll
    for (int off = 16; off < 64; off <<= 1)
#pragma unroll
      for (int j = 0; j < 8; j++) a[j] += __shfl_xor(a[j], off);

    if (sub == 0) {
      v8bf u;
#pragma unroll
      for (int j = 0; j < 8; j++) u[j] = (__bf16)(di * (a[j] + (float)ys[j]));
      int byte = (row * 256 + dc * 2) ^ ((row & 7) << 4);   // T2 XOR swizzle
      *(v8bf*)(lb + byte) = u;
    }
  }
  __syncthreads();

  // ---- phase 2: GEMM from LDS (K=128), wave -> (channel, col-half) ----
  int ch = wave >> 1, q = wave & 1;
  const __bf16* Wsec = Wp + ch * 32768;
  const float* bch = bias + ch * 256;
  int arow = lane & 15;
  int g = lane >> 4;

  v8bf af[4];
#pragma unroll
  for (int kc = 0; kc < 4; kc++) {
    int byte = (arow * 256 + g * 16 + kc * 64) ^ ((arow & 7) << 4);
    af[kc] = *(const v8bf*)(lb + byte);
  }

  int crow = blockIdx.x * 16 + (g << 2);
  float dv[4];
#pragma unroll
  for (int r = 0; r < 4; r++) dv[r] = dinv[crow + r];

#pragma unroll
  for (int c4 = 0; c4 < 8; c4++) {
    int ct = q * 8 + c4;
    v8bf bf[4];
#pragma unroll
    for (int kc = 0; kc < 4; kc++)
      bf[kc] = *(const v8bf*)(Wsec + (size_t)((kc * 16 + ct) * 64 + lane) * 8);
    v4f acc = (v4f){0.f, 0.f, 0.f, 0.f};
#pragma unroll
    for (int kc = 0; kc < 4; kc++)
      acc = __builtin_amdgcn_mfma_f32_16x16x32_bf16(af[kc], bf[kc], acc, 0, 0, 0);
    int wcol = ct * 16 + (lane & 15);     // col within channel
    float bb = bch[wcol];
#pragma unroll
    for (int r = 0; r < 4; r++) {
      float z = acc[r] + bb;
      float h = z + fmaxf(z, 0.f);
      Hd[(size_t)(crow + r) * 512 + ch * 256 + wcol] = (__bf16)(dv[r] * h);
    }
  }
}

// ---------------- FUSED boundary A: gather([N,512]) -> LDS -> dual GEMM K=256 -------
// Dynamic node pool + verified 1KB-row gather loop. Output -> OUT-REGION [N,512]
// (51.2 MB — does NOT fit in workspace; round-8 lesson).
__global__ __launch_bounds__(256) void fusedA_kernel(
    const __bf16* __restrict__ A,   // [N,512] interleaved, rows pre-scaled by dinv[row]
    const int* __restrict__ rowstart, const int* __restrict__ deg,
    const int* __restrict__ csr_src, const float* __restrict__ dinv,
    const __bf16* __restrict__ Wp,  // W1 base (2 sections of 65536)
    const float* __restrict__ bias, // [2,256]
    __bf16* __restrict__ Hd) {      // [N,512] interleaved (out region)
  __shared__ __bf16 lds[16 * 512];  // 16 KB
  __shared__ int wcnt;
  char* lb = (char*)lds;
  int wave = threadIdx.x >> 6;
  int lane = threadIdx.x & 63;
  int d0 = lane * 8;                // combined col (0..511), 16B per lane
  if (threadIdx.x == 0) wcnt = 0;
  __syncthreads();

  // ---- phase 1: dynamic node pool, full 1KB rows ----
  for (;;) {
    int row;
    if (lane == 0) row = atomicAdd(&wcnt, 1);
    row = __shfl(row, 0);
    if (row >= 16) break;
    int node = blockIdx.x * 16 + row;

    int start = rowstart[node];
    int cnt = deg[node] - 1;
    start = max(0, min(start, N_EDGES));
    cnt = max(0, min(cnt, N_EDGES - start));
    int e = start, end = start + cnt;

    float di = dinv[node];
    v8bf ys = *(const v8bf*)(A + (unsigned)(node * 512 + d0));

    float a[8];
#pragma unroll
    for (int j = 0; j < 8; j++) a[j] = 0.f;

    for (; e + 8 <= end; e += 8) {
      int s0 = csr_src[e],     s1 = csr_src[e + 1];
      int s2 = csr_src[e + 2], s3 = csr_src[e + 3];
      int s4 = csr_src[e + 4], s5 = csr_src[e + 5];
      int s6 = csr_src[e + 6], s7 = csr_src[e + 7];
      if ((unsigned)s0 >= (unsigned)N_NODES) s0 = 0;
      if ((unsigned)s1 >= (unsigned)N_NODES) s1 = 0;
      if ((unsigned)s2 >= (unsigned)N_NODES) s2 = 0;
      if ((unsigned)s3 >= (unsigned)N_NODES) s3 = 0;
      if ((unsigned)s4 >= (unsigned)N_NODES) s4 = 0;
      if ((unsigned)s5 >= (unsigned)N_NODES) s5 = 0;
      if ((unsigned)s6 >= (unsigned)N_NODES) s6 = 0;
      if ((unsigned)s7 >= (unsigned)N_NODES) s7 = 0;
      v8bf y0 = *(const v8bf*)(A + (unsigned)(s0 * 512 + d0));
      v8bf y1 = *(const v8bf*)(A + (unsigned)(s1 * 512 + d0));
      v8bf y2 = *(const v8bf*)(A + (unsigned)(s2 * 512 + d0));
      v8bf y3 = *(const v8bf*)(A + (unsigned)(s3 * 512 + d0));
      v8bf y4 = *(const v8bf*)(A + (unsigned)(s4 * 512 + d0));
      v8bf y5 = *(const v8bf*)(A + (unsigned)(s5 * 512 + d0));
      v8bf y6 = *(const v8bf*)(A + (unsigned)(s6 * 512 + d0));
      v8bf y7 = *(const v8bf*)(A + (unsigned)(s7 * 512 + d0));
#pragma unroll
      for (int j = 0; j < 8; j++)
        a[j] += (((float)y0[j] + (float)y1[j]) + ((float)y2[j] + (float)y3[j])) +
                (((float)y4[j] + (float)y5[j]) + ((float)y6[j] + (float)y7[j]));
    }
    if (e + 4 <= end) {
      int s0 = csr_src[e],     s1 = csr_src[e + 1];
      int s2 = csr_src[e + 2], s3 = csr_src[e + 3];
      if ((unsigned)s0 >= (unsigned)N_NODES) s0 = 0;
      if ((unsigned)s1 >= (unsigned)N_NODES) s1 = 0;
      if ((unsigned)s2 >= (unsigned)N_NODES) s2 = 0;
      if ((unsigned)s3 >= (unsigned)N_NODES) s3 = 0;
      v8bf y0 = *(const v8bf*)(A + (unsigned)(s0 * 512 + d0));
      v8bf y1 = *(const v8bf*)(A + (unsigned)(s1 * 512 + d0));
      v8bf y2 = *(const v8bf*)(A + (unsigned)(s2 * 512 + d0));
      v8bf y3 = *(const v8bf*)(A + (unsigned)(s3 * 512 + d0));
#pragma unroll
      for (int j = 0; j < 8; j++)
        a[j] += ((float)y0[j] + (float)y1[j]) + ((float)y2[j] + (float)y3[j]);
      e += 4;
    }
    for (; e < end; e++) {
      int s0 = csr_src[e];
      if ((unsigned)s0 >= (unsigned)N_NODES) s0 = 0;
      v8bf y0 = *(const v8bf*)(A + (unsigned)(s0 * 512 + d0));
#pragma unroll
      for (int j = 0; j < 8; j++) a[j] += (float)y0[j];
    }

    v8bf u;
#pragma unroll
    for (int j = 0; j < 8; j++) u[j] = (__bf16)(di * (a[j] + (float)ys[j]));
    int byte = (row * 1024 + lane * 16) ^ ((row & 7) << 4);   // T2 XOR swizzle
    *(v8bf*)(lb + byte) = u;
  }
  __syncthreads();

  // ---- phase 2: GEMM from LDS (K=256) ----
  int ch = wave >> 1, q = wave & 1;
  const __bf16* Wsec = Wp + ch * 65536;
  const float* bch = bias + ch * 256;
  int arow = lane & 15;
  int g = lane >> 4;

  v8bf af[8];
#pragma unroll
  for (int kc = 0; kc < 8; kc++) {
    int byte = (arow * 1024 + ch * 512 + g * 16 + kc * 64) ^ ((arow & 7) << 4);
    af[kc] = *(const v8bf*)(lb + byte);
  }

  int crow = blockIdx.x * 16 + (g << 2);
  float dv[4];
#pragma unroll
  for (int r = 0; r < 4; r++) dv[r] = dinv[crow + r];

#pragma unroll
  for (int c4 = 0; c4 < 8; c4++) {
    int ct = q * 8 + c4;
    v8bf bf[8];
#pragma unroll
    for (int kc = 0; kc < 8; kc++)
      bf[kc] = *(const v8bf*)(Wsec + (size_t)((kc * 16 + ct) * 64 + lane) * 8);
    v4f acc = (v4f){0.f, 0.f, 0.f, 0.f};
#pragma unroll
    for (int kc = 0; kc < 8; kc++)
      acc = __builtin_amdgcn_mfma_f32_16x16x32_bf16(af[kc], bf[kc], acc, 0, 0, 0);
    int wcol = ct * 16 + (lane & 15);
    float bb = bch[wcol];
#pragma unroll
    for (int r = 0; r < 4; r++) {
      float z = acc[r] + bb;
      float h = z + fmaxf(z, 0.f);
      Hd[(size_t)(crow + r) * 512 + ch * 256 + wcol] = (__bf16)(dv[r] * h);
    }
  }
}

// ---------------- standalone fused dual-channel aggregation (boundary B) ------------
// (round-6/7 verified kernel, unchanged)
__global__ __launch_bounds__(256) void agg_fused512_kernel(
    const __bf16* __restrict__ A, const int* __restrict__ rowstart,
    const int* __restrict__ deg, const int* __restrict__ csr_src,
    const float* __restrict__ dinv, __bf16* __restrict__ U) {
  int node = blockIdx.x * 4 + (threadIdx.x >> 6);
  int lane = threadIdx.x & 63;
  int d0 = lane * 8;

  int start = rowstart[node];
  int cnt = deg[node] - 1;
  start = max(0, min(start, N_EDGES));
  cnt = max(0, min(cnt, N_EDGES - start));
  int e = start, end = start + cnt;

  float di = dinv[node];
  v8bf ys = *(const v8bf*)(A + (unsigned)(node * 512 + d0));

  float a[8];
#pragma unroll
  for (int j = 0; j < 8; j++) a[j] = 0.f;

  for (; e + 8 <= end; e += 8) {
    int s0 = csr_src[e],     s1 = csr_src[e + 1];
    int s2 = csr_src[e + 2], s3 = csr_src[e + 3];
    int s4 = csr_src[e + 4], s5 = csr_src[e + 5];
    int s6 = csr_src[e + 6], s7 = csr_src[e + 7];
    if ((unsigned)s0 >= (unsigned)N_NODES) s0 = 0;
    if ((unsigned)s1 >= (unsigned)N_NODES) s1 = 0;
    if ((unsigned)s2 >= (unsigned)N_NODES) s2 = 0;
    if ((unsigned)s3 >= (unsigned)N_NODES) s3 = 0;
    if ((unsigned)s4 >= (unsigned)N_NODES) s4 = 0;
    if ((unsigned)s5 >= (unsigned)N_NODES) s5 = 0;
    if ((unsigned)s6 >= (unsigned)N_NODES) s6 = 0;
    if ((unsigned)s7 >= (unsigned)N_NODES) s7 = 0;
    v8bf y0 = *(const v8bf*)(A + (unsigned)(s0 * 512 + d0));
    v8bf y1 = *(const v8bf*)(A + (unsigned)(s1 * 512 + d0));
    v8bf y2 = *(const v8bf*)(A + (unsigned)(s2 * 512 + d0));
    v8bf y3 = *(const v8bf*)(A + (unsigned)(s3 * 512 + d0));
    v8bf y4 = *(const v8bf*)(A + (unsigned)(s4 * 512 + d0));
    v8bf y5 = *(const v8bf*)(A + (unsigned)(s5 * 512 + d0));
    v8bf y6 = *(const v8bf*)(A + (unsigned)(s6 * 512 + d0));
    v8bf y7 = *(const v8bf*)(A + (unsigned)(s7 * 512 + d0));
#pragma unroll
    for (int j = 0; j < 8; j++)
      a[j] += (((float)y0[j] + (float)y1[j]) + ((float)y2[j] + (float)y3[j])) +
              (((float)y4[j] + (float)y5[j]) + ((float)y6[j] + (float)y7[j]));
  }
  if (e + 4 <= end) {
    int s0 = csr_src[e],     s1 = csr_src[e + 1];
    int s2 = csr_src[e + 2], s3 = csr_src[e + 3];
    if ((unsigned)s0 >= (unsigned)N_NODES) s0 = 0;
    if ((unsigned)s1 >= (unsigned)N_NODES) s1 = 0;
    if ((unsigned)s2 >= (unsigned)N_NODES) s2 = 0;
    if ((unsigned)s3 >= (unsigned)N_NODES) s3 = 0;
    v8bf y0 = *(const v8bf*)(A + (unsigned)(s0 * 512 + d0));
    v8bf y1 = *(const v8bf*)(A + (unsigned)(s1 * 512 + d0));
    v8bf y2 = *(const v8bf*)(A + (unsigned)(s2 * 512 + d0));
    v8bf y3 = *(const v8bf*)(A + (unsigned)(s3 * 512 + d0));
#pragma unroll
    for (int j = 0; j < 8; j++)
      a[j] += ((float)y0[j] + (float)y1[j]) + ((float)y2[j] + (float)y3[j]);
    e += 4;
  }
  for (; e < end; e++) {
    int s0 = csr_src[e];
    if ((unsigned)s0 >= (unsigned)N_NODES) s0 = 0;
    v8bf y0 = *(const v8bf*)(A + (unsigned)(s0 * 512 + d0));
#pragma unroll
    for (int j = 0; j < 8; j++) a[j] += (float)y0[j];
  }

  v8bf u;
#pragma unroll
  for (int j = 0; j < 8; j++) u[j] = (__bf16)(di * (a[j] + (float)ys[j]));
  *(v8bf*)(U + (unsigned)(node * 512 + d0)) = u;
}

// ---------------- final GEMM: h = z + relu(z); LayerNorm(256); write f32 ------------
// (round-6/7 verified kernel, unchanged; LDA=512 interleaved A)
__global__ __launch_bounds__(256, 2) void gemm_final_kernel(
    const __bf16* __restrict__ A, const __bf16* __restrict__ Wp,
    const float* __restrict__ bias, const float* __restrict__ lnw,
    const float* __restrict__ lnb, float* __restrict__ out) {
  constexpr int KC = 8;   // K = 256
  constexpr int LDA = 512;
  __shared__ float ls1[4][16];
  __shared__ float ls2[4][16];
  int lane = threadIdx.x & 63;
  int wave = threadIdx.x >> 6;

  v8bf bfrag[KC][4];
#pragma unroll
  for (int kc = 0; kc < KC; kc++)
#pragma unroll
    for (int c4 = 0; c4 < 4; c4++)
      bfrag[kc][c4] = *(const v8bf*)(Wp + ((size_t)((kc * 16 + wave * 4 + c4) * 64 + lane)) * 8);

  int arow = lane & 15;
  int akq = (lane >> 4) * 8;
  int g = lane >> 4;
  int ccol = wave * 64 + (lane & 15);
  float bcol[4], wcol[4], lbcol[4];
#pragma unroll
  for (int c4 = 0; c4 < 4; c4++) {
    int col = ccol + c4 * 16;
    bcol[c4] = bias[col];
    wcol[c4] = lnw[col];
    lbcol[c4] = lnb[col];
  }

  for (int t = blockIdx.x; t < ROW_TILES; t += gridDim.x) {
    int row0 = t * 16;
    const __bf16* Ap = A + (size_t)(row0 + arow) * LDA + akq;
    v8bf af[KC];
#pragma unroll
    for (int kc = 0; kc < KC; kc++) af[kc] = *(const v8bf*)(Ap + kc * 32);

    v4f acc[4];
#pragma unroll
    for (int c4 = 0; c4 < 4; c4++) acc[c4] = (v4f){0.f, 0.f, 0.f, 0.f};
#pragma unroll
    for (int kc = 0; kc < KC; kc++)
#pragma unroll
      for (int c4 = 0; c4 < 4; c4++)
        acc[c4] = __builtin_amdgcn_mfma_f32_16x16x32_bf16(af[kc], bfrag[kc][c4], acc[c4], 0, 0, 0);

    float h[4][4];
#pragma unroll
    for (int c4 = 0; c4 < 4; c4++)
#pragma unroll
      for (int r = 0; r < 4; r++) {
        float z = acc[c4][r] + bcol[c4];
        h[c4][r] = z + fmaxf(z, 0.f);
      }

    float s1[4], s2[4];
#pragma unroll
    for (int r = 0; r < 4; r++) {
      s1[r] = 0.f; s2[r] = 0.f;
#pragma unroll
      for (int c4 = 0; c4 < 4; c4++) { s1[r] += h[c4][r]; s2[r] += h[c4][r] * h[c4][r]; }
    }
#pragma unroll
    for (int off = 1; off < 16; off <<= 1)
#pragma unroll
      for (int r = 0; r < 4; r++) {
        s1[r] += __shfl_xor(s1[r], off);
        s2[r] += __shfl_xor(s2[r], off);
      }
    if ((lane & 15) == 0) {
#pragma unroll
      for (int r = 0; r < 4; r++) { ls1[wave][g * 4 + r] = s1[r]; ls2[wave][g * 4 + r] = s2[r]; }
    }
    __syncthreads();
#pragma unroll
    for (int r = 0; r < 4; r++) {
      int row = g * 4 + r;
      float t1 = ls1[0][row] + ls1[1][row] + ls1[2][row] + ls1[3][row];
      float t2 = ls2[0][row] + ls2[1][row] + ls2[2][row] + ls2[3][row];
      float mean = t1 * (1.0f / 256.0f);
      float var = t2 * (1.0f / 256.0f) - mean * mean;
      float rstd = rsqrtf(fmaxf(var, 0.f) + LN_EPS);
#pragma unroll
      for (int c4 = 0; c4 < 4; c4++)
        out[(size_t)(row0 + row) * 256 + ccol + c4 * 16] =
            (h[c4][r] - mean) * rstd * wcol[c4] + lbcol[c4];
    }
    __syncthreads();   // protect LDS reuse on next tile
  }
}

__global__ void batchs_kernel(const void* __restrict__ batch, const int* __restrict__ flag,
                              float* __restrict__ ob) {
  int i = blockIdx.x * 256 + threadIdx.x;
  if (i >= N_NODES) return;
  int f = flag[0];
  int v;
  if (f) v = (int)((const long long*)batch)[i];
  else   v = ((const int*)batch)[i];
  float b = (float)v;
  ob[i] = b;
  ob[N_NODES + i] = b;
}

// ---------------- launch ----------------
// Round-7 verified choreography + dynamic node pool in fused gathers:
//   xd = dinv.*x (bf16, ws)
//   fused0:  gather(xd) -> LDS -> GEMM K=128 -> H1         [region1]
//   fusedA:  gather(H1) -> LDS -> GEMM K=256 -> H2         [region0]
//   aggB:    gather(H2) -> UC                              [region1, over dead H1]
//   final c0: reads UC cols 0-255, writes out0             [region0, over dead H2]
//   final c1: reads UC cols 256-511, writes out1           [region1, same-row overwrite]

extern "C" void kernel_launch(void* const* d_in, const int* in_sizes, int n_in,
                              void* d_out, int out_size, void* d_ws, size_t ws_size,
                              hipStream_t stream) {
  const float* x    = (const float*)d_in[0];
  const void*  edge = d_in[1];
  const void*  batch= d_in[2];
  const float* W0   = (const float*)d_in[3];
  const float* b0   = (const float*)d_in[4];
  const float* W1   = (const float*)d_in[5];
  const float* b1   = (const float*)d_in[6];
  const float* W2   = (const float*)d_in[7];
  const float* b2   = (const float*)d_in[8];
  const float* lnw  = (const float*)d_in[9];
  const float* lnb  = (const float*)d_in[10];

  // Output layout (verified R6): chunk0 = out [2,50000,256] f32, chunk1 = batchs f32.
  float* out_x = (float*)d_out;
  float* out_b = (float*)d_out + (size_t)2 * N_NODES * 256;

  // out-region scratch: each region = 51.2 MB = one [N,512] bf16 table.
  __bf16* H2 = (__bf16*)out_x;                              // region0
  __bf16* H1 = (__bf16*)(out_x + (size_t)N_NODES * 256);    // region1
  __bf16* UC = H1;                                          // region1 (after H1 is dead)

  // workspace layout — ~29.9 MB
  char* p = (char*)d_ws;
  __bf16* xd    = (__bf16*)p;  p += (size_t)N_NODES * 256 * 2;     // xd uses first 12.8 MB
  int* csr_src  = (int*)p;     p += (size_t)N_EDGES * 4;           //  3,200,000
  int* deg      = (int*)p;     p += (size_t)N_NODES * 4;
  int* cursor   = (int*)p;     p += (size_t)N_NODES * 4;
  int* rowstart = (int*)p;     p += (size_t)N_NODES * 4;
  float* dinv   = (float*)p;   p += (size_t)N_NODES * 4;
  int* flag     = (int*)p;     p += 16;
  int* gcount   = (int*)p;     p += 16;
  __bf16* Wp    = (__bf16*)p;                                      //    655,360 bytes

  const int EB = (N_EDGES + 255) / 256;   // 3125
  const int NB = (N_NODES + 255) / 256;   // 196

  probe_kernel<<<1, 64, 0, stream>>>((const int*)edge, flag);
  init_kernel<<<NB, 256, 0, stream>>>(deg, gcount);
  count_kernel<<<EB, 256, 0, stream>>>(edge, flag, deg);
  block_offsets_kernel<<<NB, 256, 0, stream>>>(deg, gcount, rowstart, cursor, dinv);
  scatter_kernel<<<EB, 256, 0, stream>>>(edge, flag, cursor, csr_src);

  pack_all_kernel<<<1280, 256, 0, stream>>>(W0, W1, W2, Wp);
  prescale_x_kernel<<<3125, 256, 0, stream>>>(x, dinv, xd);

  // layer-0: fused gather + dual GEMM K=128 -> H1 (region1)
  fused0_kernel<<<ROW_TILES, 256, 0, stream>>>(xd, rowstart, deg, csr_src, dinv,
                                               Wp, b0, H1);
  // boundary A: fused gather + dual GEMM K=256 -> H2 (region0)
  fusedA_kernel<<<ROW_TILES, 256, 0, stream>>>(H1, rowstart, deg, csr_src, dinv,
                                               Wp + 65536, b1, H2);
  // boundary B: standalone gather H2 -> UC (region1, over dead H1)
  agg_fused512_kernel<<<N_NODES / 4, 256, 0, stream>>>(H2, rowstart, deg, csr_src, dinv, UC);
  // final c0 FIRST (reads UC@r1, writes r0 over dead H2); then c1 (same-row overwrite of r1)
  gemm_final_kernel<<<512, 256, 0, stream>>>(UC, Wp + 196608, b2, lnw, lnb, out_x);
  gemm_final_kernel<<<512, 256, 0, stream>>>(UC + 256, Wp + 262144, b2 + 256, lnw, lnb,
                                             out_x + (size_t)N_NODES * 256);

  batchs_kernel<<<NB, 256, 0, stream>>>(batch, flag, out_b);
}

// Round 10
// 505.278 us; speedup vs baseline: 1.1808x; 1.1808x over previous
//
#include <hip/hip_runtime.h>
#include <hip/hip_bf16.h>

typedef __bf16 v8bf __attribute__((ext_vector_type(8)));
typedef float  v4f  __attribute__((ext_vector_type(4)));
typedef float  v2f  __attribute__((ext_vector_type(2)));

constexpr int N_NODES = 50000;
constexpr int N_EDGES = 800000;
constexpr float LN_EPS = 1e-6f;
constexpr int ROW_TILES = N_NODES / 16;   // 3125, exact

// Accumulate 8 fp8 (one uint2) into a[0..7] as f32 via HW cvt.
#define ACC_FP8X8(w, a)                                              \
  {                                                                  \
    v2f p0 = __builtin_amdgcn_cvt_pk_f32_fp8((w).x, false);          \
    v2f p1 = __builtin_amdgcn_cvt_pk_f32_fp8((w).x, true);           \
    v2f p2 = __builtin_amdgcn_cvt_pk_f32_fp8((w).y, false);          \
    v2f p3 = __builtin_amdgcn_cvt_pk_f32_fp8((w).y, true);           \
    a[0] += p0.x; a[1] += p0.y; a[2] += p1.x; a[3] += p1.y;          \
    a[4] += p2.x; a[5] += p2.y; a[6] += p3.x; a[7] += p3.y;          \
  }

__device__ __forceinline__ unsigned char f32_to_fp8(float v) {
  int pk = __builtin_amdgcn_cvt_pk_fp8_f32(v, v, 0, false);
  return (unsigned char)(pk & 0xFF);
}

// ---------------- int-width probe (robust to int32/int64 device ints) ----------------
__global__ void probe_kernel(const int* __restrict__ edge, int* __restrict__ flag) {
  int t = threadIdx.x;           // 64 lanes
  int nz = 0;
  for (int i = t * 2 + 1; i < 4096; i += 128) nz |= (edge[i] != 0);
  unsigned long long m = __ballot(nz);
  if (t == 0) flag[0] = (m == 0ull) ? 1 : 0;
}

__device__ __forceinline__ int ld_idx(const void* base, int i, int is64) {
  int v;
  if (is64) v = (int)((const long long*)base)[(long long)i];
  else      v = ((const int*)base)[i];
  if ((unsigned)v >= (unsigned)N_NODES) v = 0;   // defensive clamp
  return v;
}

// ---------------- graph preprocessing ----------------

__global__ void init_kernel(int* __restrict__ deg, int* __restrict__ gcount) {
  int i = blockIdx.x * 256 + threadIdx.x;
  if (i < N_NODES) deg[i] = 1;              // self-loop
  if (i == 0) gcount[0] = 0;
}

__global__ void count_kernel(const void* __restrict__ edge, const int* __restrict__ flag,
                             int* __restrict__ deg) {
  int e = blockIdx.x * 256 + threadIdx.x;
  if (e < N_EDGES) atomicAdd(&deg[ld_idx(edge, N_EDGES + e, flag[0])], 1);
}

__global__ __launch_bounds__(256) void block_offsets_kernel(
    const int* __restrict__ deg, int* __restrict__ gcount,
    int* __restrict__ rowstart, int* __restrict__ cursor, float* __restrict__ dinv) {
  __shared__ int ps[256];
  __shared__ int base_s;
  int tid = threadIdx.x;
  int node = blockIdx.x * 256 + tid;
  int d = (node < N_NODES) ? deg[node] : 1;
  int cnt = d - 1;                           // real in-edges for this node
  ps[tid] = cnt;
  __syncthreads();
#pragma unroll
  for (int off = 1; off < 256; off <<= 1) {
    int v = (tid >= off) ? ps[tid - off] : 0;
    __syncthreads();
    ps[tid] += v;
    __syncthreads();
  }
  if (tid == 255) base_s = atomicAdd(gcount, ps[255]);
  __syncthreads();
  int start = base_s + ps[tid] - cnt;        // exclusive within block + block base
  if (node < N_NODES) {
    rowstart[node] = start;
    cursor[node]   = start;
    dinv[node]     = rsqrtf((float)max(d, 1));
  }
}

__global__ void scatter_kernel(const void* __restrict__ edge, const int* __restrict__ flag,
                               int* __restrict__ cursor, int* __restrict__ csr_src) {
  int e = blockIdx.x * 256 + threadIdx.x;
  if (e >= N_EDGES) return;
  int f = flag[0];
  int s = ld_idx(edge, e, f);
  int d = ld_idx(edge, N_EDGES + e, f);
  int pos = atomicAdd(&cursor[d], 1);
  if ((unsigned)pos < (unsigned)N_EDGES) csr_src[pos] = s;
}

// ---------------- weight packing (fp32 -> bf16 MFMA B-fragment layout) ----------------
// Wp sections: W0c0[0] W0c1[32768] W1c0[65536] W1c1[131072] W2c0[196608] W2c1[262144]
// Within a section: Wp[((kc*16 + ct)*64 + lane)*8 + j] = W[kc*32 + (lane>>4)*8 + j][ct*16 + (lane&15)]
__global__ void pack_all_kernel(const float* __restrict__ W0, const float* __restrict__ W1,
                                const float* __restrict__ W2, __bf16* __restrict__ Wp) {
  int tid = blockIdx.x * 256 + threadIdx.x;   // 327680 threads exactly (1280 blocks)
  const float* src; int local;
  if (tid < 65536)       { src = W0 + (size_t)(tid >> 15) * (128 * 256); local = tid & 32767; }
  else if (tid < 196608) { int t2 = tid - 65536;  src = W1 + (size_t)(t2 >> 16) * 65536; local = t2 & 65535; }
  else                   { int t2 = tid - 196608; src = W2 + (size_t)(t2 >> 16) * 65536; local = t2 & 65535; }
  int j    = local & 7;
  int lane = (local >> 3) & 63;
  int ct   = (local >> 9) & 15;
  int kc   = local >> 13;
  int k    = kc * 32 + ((lane >> 4) << 3) + j;
  int col  = ct * 16 + (lane & 15);
  Wp[tid] = (__bf16)src[k * 256 + col];
}

// ---------------- x pre-scale: xd[i] = bf16(dinv[i] * x[i]), 128 dims ----------------
__global__ __launch_bounds__(256) void prescale_x_kernel(
    const float* __restrict__ x, const float* __restrict__ dinv, __bf16* __restrict__ xd) {
  int t = blockIdx.x * 256 + threadIdx.x;   // 800000 threads exactly
  int node = t >> 4;
  int d0 = (t & 15) * 8;
  float di = dinv[node];
  v4f f0 = *(const v4f*)(x + (size_t)node * 128 + d0);
  v4f f1 = *(const v4f*)(x + (size_t)node * 128 + d0 + 4);
  v8bf o;
#pragma unroll
  for (int j = 0; j < 4; j++) { o[j] = (__bf16)(di * f0[j]); o[4 + j] = (__bf16)(di * f1[j]); }
  *(v8bf*)(xd + (size_t)node * 128 + d0) = o;
}

// ---------------- FUSED layer-0: gather(xd bf16,128) -> LDS -> dual GEMM K=128 ------
// Output H1 is FP8 [N,512] (halves the next pass's compulsory gather fetch).
__global__ __launch_bounds__(256) void fused0_kernel(
    const __bf16* __restrict__ Yd, const int* __restrict__ rowstart,
    const int* __restrict__ deg, const int* __restrict__ csr_src,
    const float* __restrict__ dinv, const __bf16* __restrict__ Wp,   // W0 base (2 sections)
    const float* __restrict__ bias,                                  // [2,256]
    unsigned char* __restrict__ Hd) {                                // [N,512] fp8
  __shared__ __bf16 lds[16 * 128];   // 4 KB
  __shared__ int wcnt;
  char* lb = (char*)lds;
  int wave = threadIdx.x >> 6;
  int lane = threadIdx.x & 63;
  int sub = lane >> 4;
  int dc = (lane & 15) * 8;
  if (threadIdx.x == 0) wcnt = 0;
  __syncthreads();

  // ---- phase 1: dynamic node pool ----
  for (;;) {
    int row;
    if (lane == 0) row = atomicAdd(&wcnt, 1);
    row = __shfl(row, 0);
    if (row >= 16) break;
    int node = blockIdx.x * 16 + row;

    int start = rowstart[node];
    int cnt = deg[node] - 1;
    start = max(0, min(start, N_EDGES));
    cnt = max(0, min(cnt, N_EDGES - start));
    int e = start, end = start + cnt;

    float di = dinv[node];
    v8bf ys = *(const v8bf*)(Yd + (unsigned)(node * 128 + dc));

    float a[8];
#pragma unroll
    for (int j = 0; j < 8; j++) a[j] = 0.f;

    for (; e + 16 <= end; e += 16) {
      int s0 = csr_src[e + sub];
      int s1 = csr_src[e + 4 + sub];
      int s2 = csr_src[e + 8 + sub];
      int s3 = csr_src[e + 12 + sub];
      if ((unsigned)s0 >= (unsigned)N_NODES) s0 = 0;
      if ((unsigned)s1 >= (unsigned)N_NODES) s1 = 0;
      if ((unsigned)s2 >= (unsigned)N_NODES) s2 = 0;
      if ((unsigned)s3 >= (unsigned)N_NODES) s3 = 0;
      v8bf y0 = *(const v8bf*)(Yd + (unsigned)(s0 * 128 + dc));
      v8bf y1 = *(const v8bf*)(Yd + (unsigned)(s1 * 128 + dc));
      v8bf y2 = *(const v8bf*)(Yd + (unsigned)(s2 * 128 + dc));
      v8bf y3 = *(const v8bf*)(Yd + (unsigned)(s3 * 128 + dc));
#pragma unroll
      for (int j = 0; j < 8; j++)
        a[j] += ((float)y0[j] + (float)y1[j]) + ((float)y2[j] + (float)y3[j]);
    }
    if (e + 8 <= end) {
      int s0 = csr_src[e + sub];
      int s1 = csr_src[e + 4 + sub];
      if ((unsigned)s0 >= (unsigned)N_NODES) s0 = 0;
      if ((unsigned)s1 >= (unsigned)N_NODES) s1 = 0;
      v8bf y0 = *(const v8bf*)(Yd + (unsigned)(s0 * 128 + dc));
      v8bf y1 = *(const v8bf*)(Yd + (unsigned)(s1 * 128 + dc));
#pragma unroll
      for (int j = 0; j < 8; j++) a[j] += (float)y0[j] + (float)y1[j];
      e += 8;
    }
    if (e + 4 <= end) {
      int s0 = csr_src[e + sub];
      if ((unsigned)s0 >= (unsigned)N_NODES) s0 = 0;
      v8bf y0 = *(const v8bf*)(Yd + (unsigned)(s0 * 128 + dc));
#pragma unroll
      for (int j = 0; j < 8; j++) a[j] += (float)y0[j];
      e += 4;
    }
    int rem = end - e;
    if (sub < rem) {
      int s0 = csr_src[e + sub];
      if ((unsigned)s0 >= (unsigned)N_NODES) s0 = 0;
      v8bf y0 = *(const v8bf*)(Yd + (unsigned)(s0 * 128 + dc));
#pragma unroll
      for (int j = 0; j < 8; j++) a[j] += (float)y0[j];
    }

#pragma unroll
    for (int off = 16; off < 64; off <<= 1)
#pragma unroll
      for (int j = 0; j < 8; j++) a[j] += __shfl_xor(a[j], off);

    if (sub == 0) {
      v8bf u;
#pragma unroll
      for (int j = 0; j < 8; j++) u[j] = (__bf16)(di * (a[j] + (float)ys[j]));
      int byte = (row * 256 + dc * 2) ^ ((row & 7) << 4);   // T2 XOR swizzle
      *(v8bf*)(lb + byte) = u;
    }
  }
  __syncthreads();

  // ---- phase 2: GEMM from LDS (K=128), wave -> (channel, col-half) ----
  int ch = wave >> 1, q = wave & 1;
  const __bf16* Wsec = Wp + ch * 32768;
  const float* bch = bias + ch * 256;
  int arow = lane & 15;
  int g = lane >> 4;

  v8bf af[4];
#pragma unroll
  for (int kc = 0; kc < 4; kc++) {
    int byte = (arow * 256 + g * 16 + kc * 64) ^ ((arow & 7) << 4);
    af[kc] = *(const v8bf*)(lb + byte);
  }

  int crow = blockIdx.x * 16 + (g << 2);
  float dv[4];
#pragma unroll
  for (int r = 0; r < 4; r++) dv[r] = dinv[crow + r];

#pragma unroll
  for (int c4 = 0; c4 < 8; c4++) {
    int ct = q * 8 + c4;
    v8bf bf[4];
#pragma unroll
    for (int kc = 0; kc < 4; kc++)
      bf[kc] = *(const v8bf*)(Wsec + (size_t)((kc * 16 + ct) * 64 + lane) * 8);
    v4f acc = (v4f){0.f, 0.f, 0.f, 0.f};
#pragma unroll
    for (int kc = 0; kc < 4; kc++)
      acc = __builtin_amdgcn_mfma_f32_16x16x32_bf16(af[kc], bf[kc], acc, 0, 0, 0);
    int wcol = ct * 16 + (lane & 15);     // col within channel
    float bb = bch[wcol];
#pragma unroll
    for (int r = 0; r < 4; r++) {
      float z = acc[r] + bb;
      float h = z + fmaxf(z, 0.f);
      Hd[(size_t)(crow + r) * 512 + ch * 256 + wcol] = f32_to_fp8(dv[r] * h);
    }
  }
}

// ---------------- FUSED boundary A: gather(fp8 [N,512]) -> LDS -> dual GEMM K=256 ---
// Gather reads 512B fp8 rows (64 lanes x 8B), f32 accumulate, bf16 into LDS.
// Output H2 is FP8 [N,512].
__global__ __launch_bounds__(256) void fusedA_kernel(
    const unsigned char* __restrict__ A,   // [N,512] fp8, rows pre-scaled by dinv[row]
    const int* __restrict__ rowstart, const int* __restrict__ deg,
    const int* __restrict__ csr_src, const float* __restrict__ dinv,
    const __bf16* __restrict__ Wp,  // W1 base (2 sections of 65536)
    const float* __restrict__ bias, // [2,256]
    unsigned char* __restrict__ Hd) { // [N,512] fp8
  __shared__ __bf16 lds[16 * 512];  // 16 KB
  __shared__ int wcnt;
  char* lb = (char*)lds;
  int wave = threadIdx.x >> 6;
  int lane = threadIdx.x & 63;
  unsigned lb8 = (unsigned)(lane * 8);   // byte offset within fp8 row
  if (threadIdx.x == 0) wcnt = 0;
  __syncthreads();

  // ---- phase 1: dynamic node pool, 512B fp8 rows ----
  for (;;) {
    int row;
    if (lane == 0) row = atomicAdd(&wcnt, 1);
    row = __shfl(row, 0);
    if (row >= 16) break;
    int node = blockIdx.x * 16 + row;

    int start = rowstart[node];
    int cnt = deg[node] - 1;
    start = max(0, min(start, N_EDGES));
    cnt = max(0, min(cnt, N_EDGES - start));
    int e = start, end = start + cnt;

    float di = dinv[node];
    uint2 wys = *(const uint2*)(A + (unsigned)(node * 512) + lb8);

    float a[8];
#pragma unroll
    for (int j = 0; j < 8; j++) a[j] = 0.f;

    for (; e + 8 <= end; e += 8) {
      int s0 = csr_src[e],     s1 = csr_src[e + 1];
      int s2 = csr_src[e + 2], s3 = csr_src[e + 3];
      int s4 = csr_src[e + 4], s5 = csr_src[e + 5];
      int s6 = csr_src[e + 6], s7 = csr_src[e + 7];
      if ((unsigned)s0 >= (unsigned)N_NODES) s0 = 0;
      if ((unsigned)s1 >= (unsigned)N_NODES) s1 = 0;
      if ((unsigned)s2 >= (unsigned)N_NODES) s2 = 0;
      if ((unsigned)s3 >= (unsigned)N_NODES) s3 = 0;
      if ((unsigned)s4 >= (unsigned)N_NODES) s4 = 0;
      if ((unsigned)s5 >= (unsigned)N_NODES) s5 = 0;
      if ((unsigned)s6 >= (unsigned)N_NODES) s6 = 0;
      if ((unsigned)s7 >= (unsigned)N_NODES) s7 = 0;
      uint2 w0 = *(const uint2*)(A + (unsigned)(s0 * 512) + lb8);
      uint2 w1 = *(const uint2*)(A + (unsigned)(s1 * 512) + lb8);
      uint2 w2 = *(const uint2*)(A + (unsigned)(s2 * 512) + lb8);
      uint2 w3 = *(const uint2*)(A + (unsigned)(s3 * 512) + lb8);
      uint2 w4 = *(const uint2*)(A + (unsigned)(s4 * 512) + lb8);
      uint2 w5 = *(const uint2*)(A + (unsigned)(s5 * 512) + lb8);
      uint2 w6 = *(const uint2*)(A + (unsigned)(s6 * 512) + lb8);
      uint2 w7 = *(const uint2*)(A + (unsigned)(s7 * 512) + lb8);
      ACC_FP8X8(w0, a); ACC_FP8X8(w1, a); ACC_FP8X8(w2, a); ACC_FP8X8(w3, a);
      ACC_FP8X8(w4, a); ACC_FP8X8(w5, a); ACC_FP8X8(w6, a); ACC_FP8X8(w7, a);
    }
    if (e + 4 <= end) {
      int s0 = csr_src[e],     s1 = csr_src[e + 1];
      int s2 = csr_src[e + 2], s3 = csr_src[e + 3];
      if ((unsigned)s0 >= (unsigned)N_NODES) s0 = 0;
      if ((unsigned)s1 >= (unsigned)N_NODES) s1 = 0;
      if ((unsigned)s2 >= (unsigned)N_NODES) s2 = 0;
      if ((unsigned)s3 >= (unsigned)N_NODES) s3 = 0;
      uint2 w0 = *(const uint2*)(A + (unsigned)(s0 * 512) + lb8);
      uint2 w1 = *(const uint2*)(A + (unsigned)(s1 * 512) + lb8);
      uint2 w2 = *(const uint2*)(A + (unsigned)(s2 * 512) + lb8);
      uint2 w3 = *(const uint2*)(A + (unsigned)(s3 * 512) + lb8);
      ACC_FP8X8(w0, a); ACC_FP8X8(w1, a); ACC_FP8X8(w2, a); ACC_FP8X8(w3, a);
      e += 4;
    }
    for (; e < end; e++) {
      int s0 = csr_src[e];
      if ((unsigned)s0 >= (unsigned)N_NODES) s0 = 0;
      uint2 w0 = *(const uint2*)(A + (unsigned)(s0 * 512) + lb8);
      ACC_FP8X8(w0, a);
    }

    float ysf[8];
    {
      v2f q0 = __builtin_amdgcn_cvt_pk_f32_fp8(wys.x, false);
      v2f q1 = __builtin_amdgcn_cvt_pk_f32_fp8(wys.x, true);
      v2f q2 = __builtin_amdgcn_cvt_pk_f32_fp8(wys.y, false);
      v2f q3 = __builtin_amdgcn_cvt_pk_f32_fp8(wys.y, true);
      ysf[0] = q0.x; ysf[1] = q0.y; ysf[2] = q1.x; ysf[3] = q1.y;
      ysf[4] = q2.x; ysf[5] = q2.y; ysf[6] = q3.x; ysf[7] = q3.y;
    }
    v8bf u;
#pragma unroll
    for (int j = 0; j < 8; j++) u[j] = (__bf16)(di * (a[j] + ysf[j]));
    int byte = (row * 1024 + lane * 16) ^ ((row & 7) << 4);   // T2 XOR swizzle
    *(v8bf*)(lb + byte) = u;
  }
  __syncthreads();

  // ---- phase 2: GEMM from LDS (K=256) ----
  int ch = wave >> 1, q = wave & 1;
  const __bf16* Wsec = Wp + ch * 65536;
  const float* bch = bias + ch * 256;
  int arow = lane & 15;
  int g = lane >> 4;

  v8bf af[8];
#pragma unroll
  for (int kc = 0; kc < 8; kc++) {
    int byte = (arow * 1024 + ch * 512 + g * 16 + kc * 64) ^ ((arow & 7) << 4);
    af[kc] = *(const v8bf*)(lb + byte);
  }

  int crow = blockIdx.x * 16 + (g << 2);
  float dv[4];
#pragma unroll
  for (int r = 0; r < 4; r++) dv[r] = dinv[crow + r];

#pragma unroll
  for (int c4 = 0; c4 < 8; c4++) {
    int ct = q * 8 + c4;
    v8bf bf[8];
#pragma unroll
    for (int kc = 0; kc < 8; kc++)
      bf[kc] = *(const v8bf*)(Wsec + (size_t)((kc * 16 + ct) * 64 + lane) * 8);
    v4f acc = (v4f){0.f, 0.f, 0.f, 0.f};
#pragma unroll
    for (int kc = 0; kc < 8; kc++)
      acc = __builtin_amdgcn_mfma_f32_16x16x32_bf16(af[kc], bf[kc], acc, 0, 0, 0);
    int wcol = ct * 16 + (lane & 15);
    float bb = bch[wcol];
#pragma unroll
    for (int r = 0; r < 4; r++) {
      float z = acc[r] + bb;
      float h = z + fmaxf(z, 0.f);
      Hd[(size_t)(crow + r) * 512 + ch * 256 + wcol] = f32_to_fp8(dv[r] * h);
    }
  }
}

// ---------------- standalone dual-channel aggregation (boundary B), fp8 source ------
// One wave per node; 512B fp8 rows; f32 accumulate; bf16 [N,512] output for MFMA.
__global__ __launch_bounds__(256) void agg_fp8_kernel(
    const unsigned char* __restrict__ A, const int* __restrict__ rowstart,
    const int* __restrict__ deg, const int* __restrict__ csr_src,
    const float* __restrict__ dinv, __bf16* __restrict__ U) {
  int node = blockIdx.x * 4 + (threadIdx.x >> 6);
  int lane = threadIdx.x & 63;
  unsigned lb8 = (unsigned)(lane * 8);

  int start = rowstart[node];
  int cnt = deg[node] - 1;
  start = max(0, min(start, N_EDGES));
  cnt = max(0, min(cnt, N_EDGES - start));
  int e = start, end = start + cnt;

  float di = dinv[node];
  uint2 wys = *(const uint2*)(A + (unsigned)(node * 512) + lb8);

  float a[8];
#pragma unroll
  for (int j = 0; j < 8; j++) a[j] = 0.f;

  for (; e + 8 <= end; e += 8) {
    int s0 = csr_src[e],     s1 = csr_src[e + 1];
    int s2 = csr_src[e + 2], s3 = csr_src[e + 3];
    int s4 = csr_src[e + 4], s5 = csr_src[e + 5];
    int s6 = csr_src[e + 6], s7 = csr_src[e + 7];
    if ((unsigned)s0 >= (unsigned)N_NODES) s0 = 0;
    if ((unsigned)s1 >= (unsigned)N_NODES) s1 = 0;
    if ((unsigned)s2 >= (unsigned)N_NODES) s2 = 0;
    if ((unsigned)s3 >= (unsigned)N_NODES) s3 = 0;
    if ((unsigned)s4 >= (unsigned)N_NODES) s4 = 0;
    if ((unsigned)s5 >= (unsigned)N_NODES) s5 = 0;
    if ((unsigned)s6 >= (unsigned)N_NODES) s6 = 0;
    if ((unsigned)s7 >= (unsigned)N_NODES) s7 = 0;
    uint2 w0 = *(const uint2*)(A + (unsigned)(s0 * 512) + lb8);
    uint2 w1 = *(const uint2*)(A + (unsigned)(s1 * 512) + lb8);
    uint2 w2 = *(const uint2*)(A + (unsigned)(s2 * 512) + lb8);
    uint2 w3 = *(const uint2*)(A + (unsigned)(s3 * 512) + lb8);
    uint2 w4 = *(const uint2*)(A + (unsigned)(s4 * 512) + lb8);
    uint2 w5 = *(const uint2*)(A + (unsigned)(s5 * 512) + lb8);
    uint2 w6 = *(const uint2*)(A + (unsigned)(s6 * 512) + lb8);
    uint2 w7 = *(const uint2*)(A + (unsigned)(s7 * 512) + lb8);
    ACC_FP8X8(w0, a); ACC_FP8X8(w1, a); ACC_FP8X8(w2, a); ACC_FP8X8(w3, a);
    ACC_FP8X8(w4, a); ACC_FP8X8(w5, a); ACC_FP8X8(w6, a); ACC_FP8X8(w7, a);
  }
  if (e + 4 <= end) {
    int s0 = csr_src[e],     s1 = csr_src[e + 1];
    int s2 = csr_src[e + 2], s3 = csr_src[e + 3];
    if ((unsigned)s0 >= (unsigned)N_NODES) s0 = 0;
    if ((unsigned)s1 >= (unsigned)N_NODES) s1 = 0;
    if ((unsigned)s2 >= (unsigned)N_NODES) s2 = 0;
    if ((unsigned)s3 >= (unsigned)N_NODES) s3 = 0;
    uint2 w0 = *(const uint2*)(A + (unsigned)(s0 * 512) + lb8);
    uint2 w1 = *(const uint2*)(A + (unsigned)(s1 * 512) + lb8);
    uint2 w2 = *(const uint2*)(A + (unsigned)(s2 * 512) + lb8);
    uint2 w3 = *(const uint2*)(A + (unsigned)(s3 * 512) + lb8);
    ACC_FP8X8(w0, a); ACC_FP8X8(w1, a); ACC_FP8X8(w2, a); ACC_FP8X8(w3, a);
    e += 4;
  }
  for (; e < end; e++) {
    int s0 = csr_src[e];
    if ((unsigned)s0 >= (unsigned)N_NODES) s0 = 0;
    uint2 w0 = *(const uint2*)(A + (unsigned)(s0 * 512) + lb8);
    ACC_FP8X8(w0, a);
  }

  float ysf[8];
  {
    v2f q0 = __builtin_amdgcn_cvt_pk_f32_fp8(wys.x, false);
    v2f q1 = __builtin_amdgcn_cvt_pk_f32_fp8(wys.x, true);
    v2f q2 = __builtin_amdgcn_cvt_pk_f32_fp8(wys.y, false);
    v2f q3 = __builtin_amdgcn_cvt_pk_f32_fp8(wys.y, true);
    ysf[0] = q0.x; ysf[1] = q0.y; ysf[2] = q1.x; ysf[3] = q1.y;
    ysf[4] = q2.x; ysf[5] = q2.y; ysf[6] = q3.x; ysf[7] = q3.y;
  }
  v8bf u;
#pragma unroll
  for (int j = 0; j < 8; j++) u[j] = (__bf16)(di * (a[j] + ysf[j]));
  *(v8bf*)(U + (unsigned)(node * 512) + (unsigned)(lane * 8)) = u;
}

// ---------------- final GEMM: h = z + relu(z); LayerNorm(256); write f32 ------------
// (verified kernel, unchanged; LDA=512 interleaved bf16 A)
__global__ __launch_bounds__(256, 2) void gemm_final_kernel(
    const __bf16* __restrict__ A, const __bf16* __restrict__ Wp,
    const float* __restrict__ bias, const float* __restrict__ lnw,
    const float* __restrict__ lnb, float* __restrict__ out) {
  constexpr int KC = 8;   // K = 256
  constexpr int LDA = 512;
  __shared__ float ls1[4][16];
  __shared__ float ls2[4][16];
  int lane = threadIdx.x & 63;
  int wave = threadIdx.x >> 6;

  v8bf bfrag[KC][4];
#pragma unroll
  for (int kc = 0; kc < KC; kc++)
#pragma unroll
    for (int c4 = 0; c4 < 4; c4++)
      bfrag[kc][c4] = *(const v8bf*)(Wp + ((size_t)((kc * 16 + wave * 4 + c4) * 64 + lane)) * 8);

  int arow = lane & 15;
  int akq = (lane >> 4) * 8;
  int g = lane >> 4;
  int ccol = wave * 64 + (lane & 15);
  float bcol[4], wcol[4], lbcol[4];
#pragma unroll
  for (int c4 = 0; c4 < 4; c4++) {
    int col = ccol + c4 * 16;
    bcol[c4] = bias[col];
    wcol[c4] = lnw[col];
    lbcol[c4] = lnb[col];
  }

  for (int t = blockIdx.x; t < ROW_TILES; t += gridDim.x) {
    int row0 = t * 16;
    const __bf16* Ap = A + (size_t)(row0 + arow) * LDA + akq;
    v8bf af[KC];
#pragma unroll
    for (int kc = 0; kc < KC; kc++) af[kc] = *(const v8bf*)(Ap + kc * 32);

    v4f acc[4];
#pragma unroll
    for (int c4 = 0; c4 < 4; c4++) acc[c4] = (v4f){0.f, 0.f, 0.f, 0.f};
#pragma unroll
    for (int kc = 0; kc < KC; kc++)
#pragma unroll
      for (int c4 = 0; c4 < 4; c4++)
        acc[c4] = __builtin_amdgcn_mfma_f32_16x16x32_bf16(af[kc], bfrag[kc][c4], acc[c4], 0, 0, 0);

    float h[4][4];
#pragma unroll
    for (int c4 = 0; c4 < 4; c4++)
#pragma unroll
      for (int r = 0; r < 4; r++) {
        float z = acc[c4][r] + bcol[c4];
        h[c4][r] = z + fmaxf(z, 0.f);
      }

    float s1[4], s2[4];
#pragma unroll
    for (int r = 0; r < 4; r++) {
      s1[r] = 0.f; s2[r] = 0.f;
#pragma unroll
      for (int c4 = 0; c4 < 4; c4++) { s1[r] += h[c4][r]; s2[r] += h[c4][r] * h[c4][r]; }
    }
#pragma unroll
    for (int off = 1; off < 16; off <<= 1)
#pragma unroll
      for (int r = 0; r < 4; r++) {
        s1[r] += __shfl_xor(s1[r], off);
        s2[r] += __shfl_xor(s2[r], off);
      }
    if ((lane & 15) == 0) {
#pragma unroll
      for (int r = 0; r < 4; r++) { ls1[wave][g * 4 + r] = s1[r]; ls2[wave][g * 4 + r] = s2[r]; }
    }
    __syncthreads();
#pragma unroll
    for (int r = 0; r < 4; r++) {
      int row = g * 4 + r;
      float t1 = ls1[0][row] + ls1[1][row] + ls1[2][row] + ls1[3][row];
      float t2 = ls2[0][row] + ls2[1][row] + ls2[2][row] + ls2[3][row];
      float mean = t1 * (1.0f / 256.0f);
      float var = t2 * (1.0f / 256.0f) - mean * mean;
      float rstd = rsqrtf(fmaxf(var, 0.f) + LN_EPS);
#pragma unroll
      for (int c4 = 0; c4 < 4; c4++)
        out[(size_t)(row0 + row) * 256 + ccol + c4 * 16] =
            (h[c4][r] - mean) * rstd * wcol[c4] + lbcol[c4];
    }
    __syncthreads();   // protect LDS reuse on next tile
  }
}

__global__ void batchs_kernel(const void* __restrict__ batch, const int* __restrict__ flag,
                              float* __restrict__ ob) {
  int i = blockIdx.x * 256 + threadIdx.x;
  if (i >= N_NODES) return;
  int f = flag[0];
  int v;
  if (f) v = (int)((const long long*)batch)[i];
  else   v = ((const int*)batch)[i];
  float b = (float)v;
  ob[i] = b;
  ob[N_NODES + i] = b;
}

// ---------------- launch ----------------
// fp8 inter-layer tables (halves the compulsory cross-XCD gather re-fetch):
//   xd = dinv.*x (bf16, ws)
//   fused0:  gather(xd bf16) -> LDS -> GEMM K=128 -> H1 fp8   [region1 1st half, 25.6MB]
//   fusedA:  gather(H1 fp8)  -> LDS -> GEMM K=256 -> H2 fp8   [region1 2nd half, 25.6MB]
//   aggB:    gather(H2 fp8)  -> UC bf16 [N,512]               [region0, 51.2MB]
//   final c1: reads UC cols 256.., writes out1                [region1, H1/H2 dead]
//   final c0: reads UC cols 0-255, writes out0                [region0, row-aligned
//                                                              self-overwrite — safe]

extern "C" void kernel_launch(void* const* d_in, const int* in_sizes, int n_in,
                              void* d_out, int out_size, void* d_ws, size_t ws_size,
                              hipStream_t stream) {
  const float* x    = (const float*)d_in[0];
  const void*  edge = d_in[1];
  const void*  batch= d_in[2];
  const float* W0   = (const float*)d_in[3];
  const float* b0   = (const float*)d_in[4];
  const float* W1   = (const float*)d_in[5];
  const float* b1   = (const float*)d_in[6];
  const float* W2   = (const float*)d_in[7];
  const float* b2   = (const float*)d_in[8];
  const float* lnw  = (const float*)d_in[9];
  const float* lnb  = (const float*)d_in[10];

  // Output layout (verified R6): chunk0 = out [2,50000,256] f32, chunk1 = batchs f32.
  float* out_x = (float*)d_out;
  float* out_b = (float*)d_out + (size_t)2 * N_NODES * 256;

  // region0 (51.2 MB): UC bf16 [N,512], later overwritten by out0 (c0 last).
  // region1 (51.2 MB): H1 fp8 [N,512] (25.6 MB) + H2 fp8 [N,512] (25.6 MB),
  //                    later overwritten by out1 (c1 after aggB).
  __bf16*        UC = (__bf16*)out_x;
  unsigned char* H1 = (unsigned char*)(out_x + (size_t)N_NODES * 256);
  unsigned char* H2 = H1 + (size_t)N_NODES * 512;

  // workspace layout — ~29.9 MB
  char* p = (char*)d_ws;
  __bf16* xd    = (__bf16*)p;  p += (size_t)N_NODES * 256 * 2;     // xd uses first 12.8 MB
  int* csr_src  = (int*)p;     p += (size_t)N_EDGES * 4;           //  3,200,000
  int* deg      = (int*)p;     p += (size_t)N_NODES * 4;
  int* cursor   = (int*)p;     p += (size_t)N_NODES * 4;
  int* rowstart = (int*)p;     p += (size_t)N_NODES * 4;
  float* dinv   = (float*)p;   p += (size_t)N_NODES * 4;
  int* flag     = (int*)p;     p += 16;
  int* gcount   = (int*)p;     p += 16;
  __bf16* Wp    = (__bf16*)p;                                      //    655,360 bytes

  const int EB = (N_EDGES + 255) / 256;   // 3125
  const int NB = (N_NODES + 255) / 256;   // 196

  probe_kernel<<<1, 64, 0, stream>>>((const int*)edge, flag);
  init_kernel<<<NB, 256, 0, stream>>>(deg, gcount);
  count_kernel<<<EB, 256, 0, stream>>>(edge, flag, deg);
  block_offsets_kernel<<<NB, 256, 0, stream>>>(deg, gcount, rowstart, cursor, dinv);
  scatter_kernel<<<EB, 256, 0, stream>>>(edge, flag, cursor, csr_src);

  pack_all_kernel<<<1280, 256, 0, stream>>>(W0, W1, W2, Wp);
  prescale_x_kernel<<<3125, 256, 0, stream>>>(x, dinv, xd);

  // layer-0: fused gather + dual GEMM K=128 -> H1 fp8 (region1 1st half)
  fused0_kernel<<<ROW_TILES, 256, 0, stream>>>(xd, rowstart, deg, csr_src, dinv,
                                               Wp, b0, H1);
  // boundary A: fused gather(fp8) + dual GEMM K=256 -> H2 fp8 (region1 2nd half)
  fusedA_kernel<<<ROW_TILES, 256, 0, stream>>>(H1, rowstart, deg, csr_src, dinv,
                                               Wp + 65536, b1, H2);
  // boundary B: standalone gather(fp8) H2 -> UC bf16 (region0)
  agg_fp8_kernel<<<N_NODES / 4, 256, 0, stream>>>(H2, rowstart, deg, csr_src, dinv, UC);
  // final c1 FIRST (reads UC@r0 cols 256.., writes r1 over dead H1/H2);
  // then c0 (reads UC@r0, row-aligned self-overwrite of r0)
  gemm_final_kernel<<<512, 256, 0, stream>>>(UC + 256, Wp + 262144, b2 + 256, lnw, lnb,
                                             out_x + (size_t)N_NODES * 256);
  gemm_final_kernel<<<512, 256, 0, stream>>>(UC, Wp + 196608, b2, lnw, lnb, out_x);

  batchs_kernel<<<NB, 256, 0, stream>>>(batch, flag, out_b);
}